// Round 5
// baseline (596.023 us; speedup 1.0000x reference)
//
#include <hip/hip_runtime.h>
#include <hip/hip_bf16.h>

typedef unsigned short u16;
typedef unsigned int u32;
typedef __attribute__((ext_vector_type(8))) short short8;
typedef __attribute__((ext_vector_type(4))) float floatx4;

__device__ inline float bf2f(u16 u) { union { u32 i; float f; } v; v.i = ((u32)u) << 16; return v.f; }
__device__ inline u16 f2bf(float f) {
    union { float f; u32 i; } v; v.f = f;
    u32 lsb = (v.i >> 16) & 1u;
    v.i += 0x7fffu + lsb;              // round-to-nearest-even
    return (u16)(v.i >> 16);
}

__device__ inline void ld8(u16* dst, const float* src) {
    const float4 a = *(const float4*)src;
    const float4 b = *(const float4*)(src + 4);
    uint4 q;
    q.x = (u32)f2bf(a.x) | ((u32)f2bf(a.y) << 16);
    q.y = (u32)f2bf(a.z) | ((u32)f2bf(a.w) << 16);
    q.z = (u32)f2bf(b.x) | ((u32)f2bf(b.y) << 16);
    q.w = (u32)f2bf(b.z) | ((u32)f2bf(b.w) << 16);
    *(uint4*)dst = q;
}

// ---------------------------------------------------------------------------
// NT GEMM, bf16 in / fp32 MFMA accum, REGISTER-PREFETCH pipeline:
//   prologue: load tile0 -> regs
//   loop:     regs -> LDS; barrier; issue loads tile k+1 -> regs;
//             ds_read frags; MFMA(tile k); barrier
// The vmcnt wait for the prefetch lands at the regs->LDS store of the NEXT
// iteration — i.e. AFTER this iteration's MFMAs — overlapping ~900-cyc HBM
// latency with compute. 256 thr = 4 waves (2x2 of 64x64).
// zlog: split-K over z — zh=z>>zlog batch, zk=z&mask K-chunk.
// ---------------------------------------------------------------------------
template <int BM, int BN, class Epi>
__global__ __launch_bounds__(256) void gemm_nt(const u16* __restrict__ A, const u16* __restrict__ B,
                                               long sAz, long sBz, int lda, int ldb, int K, int zlog, Epi epi)
{
    constexpr int LK = 40;
    __shared__ __align__(16) u16 As[BM * LK];
    __shared__ __align__(16) u16 Bs[BN * LK];
    constexpr int NA = BM * 4 / 256, NB = BN * 4 / 256;
    const int tid  = threadIdx.x;
    const int lane = tid & 63;
    const int wave = tid >> 6;
    const int z    = blockIdx.z;
    const int zh   = z >> zlog;
    const int zk   = z & ((1 << zlog) - 1);
    const long row0 = (long)blockIdx.y * BM;
    const long col0 = (long)blockIdx.x * BN;
    const u16* Ab = A + (long)zh * sAz + row0 * lda + (long)zk * K;
    const u16* Bb = B + (long)zh * sBz + col0 * ldb + (long)zk * K;
    constexpr int WM = BM / 2, WN = BN / 2, TM = WM / 16, TN = WN / 16;
    const int wm = (wave >> 1) * WM;
    const int wn = (wave & 1) * WN;
    const int l15 = lane & 15;
    const int quad = lane >> 4;

    floatx4 acc[TM][TN];
#pragma unroll
    for (int i = 0; i < TM; i++)
#pragma unroll
        for (int j = 0; j < TN; j++) acc[i][j] = (floatx4){0.f, 0.f, 0.f, 0.f};

    uint4 ra[NA], rb[NB];
    auto loadAB = [&](int k0) {
#pragma unroll
        for (int t = 0; t < NA; t++) {
            int c = tid + t * 256; int r = c >> 2, kc = (c & 3) << 3;
            ra[t] = *(const uint4*)(Ab + (long)r * lda + k0 + kc);
        }
#pragma unroll
        for (int t = 0; t < NB; t++) {
            int c = tid + t * 256; int r = c >> 2, kc = (c & 3) << 3;
            rb[t] = *(const uint4*)(Bb + (long)r * ldb + k0 + kc);
        }
    };

    loadAB(0);
    const int nIter = K >> 5;
    for (int ki = 0; ki < nIter; ki++) {
#pragma unroll
        for (int t = 0; t < NA; t++) {
            int c = tid + t * 256;
            *(uint4*)(&As[(c >> 2) * LK + ((c & 3) << 3)]) = ra[t];
        }
#pragma unroll
        for (int t = 0; t < NB; t++) {
            int c = tid + t * 256;
            *(uint4*)(&Bs[(c >> 2) * LK + ((c & 3) << 3)]) = rb[t];
        }
        __syncthreads();
        if (ki + 1 < nIter) loadAB((ki + 1) << 5);
        short8 af[TM], bfr[TN];
#pragma unroll
        for (int t = 0; t < TM; t++) af[t] = *(const short8*)(&As[(wm + t * 16 + l15) * LK + quad * 8]);
#pragma unroll
        for (int t = 0; t < TN; t++) bfr[t] = *(const short8*)(&Bs[(wn + t * 16 + l15) * LK + quad * 8]);
#pragma unroll
        for (int i = 0; i < TM; i++)
#pragma unroll
            for (int j = 0; j < TN; j++)
                acc[i][j] = __builtin_amdgcn_mfma_f32_16x16x32_bf16(af[i], bfr[j], acc[i][j], 0, 0, 0);
        __syncthreads();
    }
#pragma unroll
    for (int i = 0; i < TM; i++)
#pragma unroll
        for (int j = 0; j < TN; j++)
#pragma unroll
            for (int r = 0; r < 4; r++) {
                int row = (int)row0 + wm + i * 16 + quad * 4 + r;
                int col = (int)col0 + wn + j * 16 + l15;
                epi(zh, row, col, acc[i][j][r]);
            }
}

// --- epilogues -------------------------------------------------------------
struct EpiBiasBF {  // C[row*ldc+col] = v + bias[col], bf16 out (sk / sq)
    u16* C; const float* bias; int ldc;
    __device__ void operator()(int, int row, int col, float v) const {
        C[(long)row * ldc + col] = f2bf(v + bias[col]);
    }
};
struct EpiQ {  // rows=(r,i) cols=(h,d) -> Qw[h][i][r*64+d] scaled by w[i,h,r]/8
    u16* Qw; const float* w;
    __device__ void operator()(int, int row, int col, float v) const {
        int r = row >> 9, i = row & 511, h = col >> 6, d = col & 63;
        float s = w[((long)(i * 8 + h)) * 64 + r] * 0.125f;
        Qw[(long)h * 2097152 + (long)i * 4096 + r * 64 + d] = f2bf(v * s);
    }
};
struct EpiKV {  // rows=(r,j) cols 0..511 -> Kp[h][j][rd]; 512..1023 -> Vp[h][j][rd]
    u16* Kp; u16* Vp;
    __device__ void operator()(int, int row, int col, float v) const {
        int r = row >> 9, j = row & 511, d = col & 63;
        u16 val = f2bf(v);
        if (col < 512) Kp[(long)(col >> 6) * 2097152 + (long)j * 4096 + r * 64 + d] = val;
        else           Vp[(long)((col - 512) >> 6) * 2097152 + (long)j * 4096 + r * 64 + d] = val;
    }
};
struct EpiDotsAtomic {  // dots[zh][row][col] += v (pb already resident), fp32
    float* pbdots;
    __device__ void operator()(int zh, int row, int col, float v) const {
        atomicAdd(pbdots + (long)zh * 262144 + (long)row * 512 + col, v);
    }
};
struct EpiPV {  // rows=i, cols=(r,d), z=h -> O2[(r*512+i)][(h*64+d)] bf16
    u16* O2;
    __device__ void operator()(int zh, int row, int col, float v) const {
        int r = col >> 6, d = col & 63;
        O2[((long)r * 512 + row) * 512 + zh * 64 + d] = f2bf(v);
    }
};
struct EpiOut {  // final: out[row*128+col] = v + bo[col], fp32
    float* out; const float* bo;
    __device__ void operator()(int, int row, int col, float v) const {
        out[(long)row * 128 + col] = v + bo[col];
    }
};

// ---------------------------------------------------------------------------
// fp32 -> bf16 bulk convert (8 elems/thread, coalesced)
// ---------------------------------------------------------------------------
__global__ __launch_bounds__(256) void f2bf_kernel(const float* __restrict__ src, u16* __restrict__ dst)
{
    long i = ((long)blockIdx.x * 256 + threadIdx.x) * 8;
    ld8(dst + i, src + i);
}

// ---------------------------------------------------------------------------
// small transpose: src (R x C, fp32) -> dst (C x R, bf16), 32x32 LDS tiles
// ---------------------------------------------------------------------------
__global__ __launch_bounds__(256) void transpose_to_bf16(const float* __restrict__ src, u16* __restrict__ dst,
                                                         int R, int C)
{
    __shared__ u16 t[32][33];
    int c0 = blockIdx.x * 32, r0 = blockIdx.y * 32;
    int tx = threadIdx.x, ty = threadIdx.y;  // 32 x 8
#pragma unroll
    for (int i = 0; i < 32; i += 8) t[ty + i][tx] = f2bf(src[(long)(r0 + ty + i) * C + c0 + tx]);
    __syncthreads();
#pragma unroll
    for (int i = 0; i < 32; i += 8) dst[(long)(c0 + ty + i) * R + r0 + tx] = t[tx][ty + i];
}

// ---------------------------------------------------------------------------
// fast bf16 transpose: 64x64 tiles, 16 B lane transfers both ways, z-batched
// ---------------------------------------------------------------------------
__global__ __launch_bounds__(256) void transpose64(const u16* __restrict__ src, u16* __restrict__ dst,
                                                   long ss, long ds, int R, int C)
{
    __shared__ __align__(16) u16 t[64][72];
    const u16* s = src + (long)blockIdx.z * ss;
    u16* d = dst + (long)blockIdx.z * ds;
    int c0 = blockIdx.x * 64, r0 = blockIdx.y * 64;
    int tid = threadIdx.x;
    int row = tid >> 3, ch = tid & 7;
#pragma unroll
    for (int p = 0; p < 2; p++) {
        int r = row + p * 32;
        *(uint4*)&t[r][ch * 8] = *(const uint4*)(s + (long)(r0 + r) * C + c0 + ch * 8);
    }
    __syncthreads();
#pragma unroll
    for (int p = 0; p < 2; p++) {
        int cc = row + p * 32;
        u16 tmp[8];
#pragma unroll
        for (int j = 0; j < 8; j++) tmp[j] = t[ch * 8 + j][cc];
        *(uint4*)(d + (long)(c0 + cc) * R + r0 + ch * 8) = *(uint4*)tmp;
    }
}

// ---------------------------------------------------------------------------
// Tie-row weights: wave per (i,h); lane = r. logit = <sq[i,h,:],sk[r,i,h,:]>/4
// ---------------------------------------------------------------------------
__global__ __launch_bounds__(256) void rowweight_kernel(const u16* __restrict__ sk, const u16* __restrict__ sq,
                                                        float* __restrict__ w)
{
    int wid = blockIdx.x * 4 + (threadIdx.x >> 6);  // 0..4095 = i*8+h
    int lane = threadIdx.x & 63;                    // r
    int i = wid >> 3, h = wid & 7;
    const u16* sqp = sq + i * 128 + h * 16;
    const u16* skp = sk + ((long)lane * 512 + i) * 128 + h * 16;
    float dot = 0.f;
#pragma unroll
    for (int c = 0; c < 16; c++) dot += bf2f(sqp[c]) * bf2f(skp[c]);
    float logit = dot * 0.25f;
    float m = logit;
#pragma unroll
    for (int o = 32; o > 0; o >>= 1) m = fmaxf(m, __shfl_xor(m, o));
    float e = __expf(logit - m);
    float ssum = e;
#pragma unroll
    for (int o = 32; o > 0; o >>= 1) ssum += __shfl_xor(ssum, o);
    w[(long)wid * 64 + lane] = e / ssum;
}

// ---------------------------------------------------------------------------
// pb prep: Wg[c*8+h] = g[c]*Wp[c*8+h]; SB[h]=sum g*W, SB[8+h]=sum b*W. 1 block.
// ---------------------------------------------------------------------------
__global__ __launch_bounds__(256) void pbprep_kernel(const float* __restrict__ g, const float* __restrict__ b,
                                                     const float* __restrict__ Wp, float* __restrict__ Wg,
                                                     float* __restrict__ SB)
{
    int tid = threadIdx.x;
    for (int t = tid; t < 1024; t += 256) Wg[t] = g[t >> 3] * Wp[t];
    if (tid < 16) {
        int h = tid & 7;
        const float* src = (tid < 8) ? g : b;
        float s = 0.f;
        for (int c = 0; c < 128; c++) s += src[c] * Wp[c * 8 + h];
        SB[tid] = s;
    }
}

// ---------------------------------------------------------------------------
// pair_bias LN + Linear(128->8), LDS-staged, coalesced. 64 rows per block.
// acc_h = rstd*(dot(v,Wg_h) - mu*S_h) + B_h
// ---------------------------------------------------------------------------
__global__ __launch_bounds__(256) void pb_kernel(const float* __restrict__ pair, const float* __restrict__ Wg,
                                                 const float* __restrict__ SB, float* __restrict__ pb)
{
    __shared__ __align__(16) float Ls[64 * 132];
    __shared__ float sWg[1024];
    __shared__ float sSB[16];
    int tid = threadIdx.x;
    for (int t = tid; t < 1024; t += 256) sWg[t] = Wg[t];
    if (tid < 16) sSB[tid] = SB[tid];
    long base = (long)blockIdx.x * 8192;  // 64 rows * 128
    const float4* src = (const float4*)(pair + base);
#pragma unroll
    for (int k = 0; k < 8; k++) {
        int e = tid + k * 256;               // float4 index in tile, 0..2047
        float4 v = src[e];
        int r = e >> 5, c = (e & 31) << 2;
        *(float4*)(&Ls[r * 132 + c]) = v;
    }
    __syncthreads();
    int r = tid >> 2, sub = tid & 3;
    const float* row = &Ls[r * 132];
    float sum = 0.f, sqs = 0.f;
#pragma unroll
    for (int k = 0; k < 8; k++) {
        float4 v = *(const float4*)(&row[sub * 32 + k * 4]);
        sum += v.x + v.y + v.z + v.w;
        sqs += v.x * v.x + v.y * v.y + v.z * v.z + v.w * v.w;
    }
    sum += __shfl_xor(sum, 1); sqs += __shfl_xor(sqs, 1);
    sum += __shfl_xor(sum, 2); sqs += __shfl_xor(sqs, 2);
    float mu = sum * (1.f / 128.f);
    float var = sqs * (1.f / 128.f) - mu * mu;
    float rstd = rsqrtf(var + 1e-5f);
    int h0 = sub * 2;
    float a0 = 0.f, a1 = 0.f;
#pragma unroll
    for (int k = 0; k < 32; k++) {
        float4 v = *(const float4*)(&row[k * 4]);
        int c = k * 4;
        a0 += v.x * sWg[c * 8 + h0]     + v.y * sWg[(c + 1) * 8 + h0]
            + v.z * sWg[(c + 2) * 8 + h0] + v.w * sWg[(c + 3) * 8 + h0];
        a1 += v.x * sWg[c * 8 + h0 + 1]     + v.y * sWg[(c + 1) * 8 + h0 + 1]
            + v.z * sWg[(c + 2) * 8 + h0 + 1] + v.w * sWg[(c + 3) * 8 + h0 + 1];
    }
    long idx = (long)blockIdx.x * 64 + r;
    pb[(long)h0 * 262144 + idx]       = rstd * (a0 - mu * sSB[h0])     + sSB[8 + h0];
    pb[(long)(h0 + 1) * 262144 + idx] = rstd * (a1 - mu * sSB[h0 + 1]) + sSB[8 + h0 + 1];
}

// ---------------------------------------------------------------------------
// Row softmax over 512 cols; wave per row (h*512+i). fp32 in, bf16 out.
// ---------------------------------------------------------------------------
__global__ __launch_bounds__(256) void softmax_kernel(const float* __restrict__ dots, u16* __restrict__ attn)
{
    int row = blockIdx.x * 4 + (threadIdx.x >> 6);
    int lane = threadIdx.x & 63;
    const float* dp = dots + (long)row * 512;
    float v[8];
#pragma unroll
    for (int k = 0; k < 8; k++) v[k] = dp[k * 64 + lane];
    float m = v[0];
#pragma unroll
    for (int k = 1; k < 8; k++) m = fmaxf(m, v[k]);
#pragma unroll
    for (int o = 32; o > 0; o >>= 1) m = fmaxf(m, __shfl_xor(m, o));
    float s = 0.f;
#pragma unroll
    for (int k = 0; k < 8; k++) { v[k] = __expf(v[k] - m); s += v[k]; }
#pragma unroll
    for (int o = 32; o > 0; o >>= 1) s += __shfl_xor(s, o);
    float inv = 1.f / s;
    u16* ap = attn + (long)row * 512;
#pragma unroll
    for (int k = 0; k < 8; k++) ap[k * 64 + lane] = f2bf(v[k] * inv);
}

// ---------------------------------------------------------------------------
extern "C" void kernel_launch(void* const* d_in, const int* in_sizes, int n_in,
                              void* d_out, int out_size, void* d_ws, size_t ws_size,
                              hipStream_t stream)
{
    const float* x    = (const float*)d_in[0];
    const float* pair = (const float*)d_in[1];
    const float* Wq   = (const float*)d_in[2];
    const float* Wkv  = (const float*)d_in[3];
    const float* Wo   = (const float*)d_in[4];
    const float* bo   = (const float*)d_in[5];
    const float* lng  = (const float*)d_in[6];
    const float* lnb  = (const float*)d_in[7];
    const float* Wp   = (const float*)d_in[8];
    const float* Wsq  = (const float*)d_in[9];
    const float* bsq  = (const float*)d_in[10];
    const float* Wsk  = (const float*)d_in[11];
    const float* bsk  = (const float*)d_in[12];
    float* out = (float*)d_out;

    char* ws = (char*)d_ws;
    size_t off = 0;
    auto alloc = [&](size_t bytes) -> char* {
        char* p = ws + off; off += (bytes + 255) & ~(size_t)255; return p;
    };
    u16* WqT  = (u16*)alloc(512 * 128 * 2);
    u16* WkvT = (u16*)alloc(1024 * 128 * 2);
    u16* WskT = (u16*)alloc(128 * 128 * 2);
    u16* WsqT = (u16*)alloc(128 * 128 * 2);
    u16* WoT  = (u16*)alloc(128 * 512 * 2);
    u16* xbf  = (u16*)alloc((size_t)32768 * 128 * 2);
    u16* sk   = (u16*)alloc((size_t)32768 * 128 * 2);   // later reused as attn
    u16* sq   = (u16*)alloc(512 * 128 * 2);
    float* w  = (float*)alloc((size_t)4096 * 64 * 4);
    float* Wg = (float*)alloc(1024 * 4);
    float* SB = (float*)alloc(16 * 4);
    u16* bufA = (u16*)alloc((size_t)8 * 512 * 4096 * 2);  // Vp, then Qw
    u16* bufB = (u16*)alloc((size_t)8 * 512 * 4096 * 2);  // Kp, then O2
    u16* Vt   = (u16*)alloc((size_t)8 * 4096 * 512 * 2);
    float* pbd = (float*)alloc((size_t)8 * 512 * 512 * 4);  // pb, then dots in-place
    u16* attn = sk;  // alias: sk dead after rowweight_kernel

    dim3 blk(256);
    dim3 tb(32, 8);

    // 0) x -> bf16 once; pb prep
    f2bf_kernel<<<dim3(2048), blk, 0, stream>>>(x, xbf);
    pbprep_kernel<<<dim3(1), blk, 0, stream>>>(lng, lnb, Wp, Wg, SB);

    // 1) weight transposes (K x N fp32 -> N x K bf16)
    transpose_to_bf16<<<dim3(16, 4, 1), tb, 0, stream>>>(Wq,  WqT,  128, 512);
    transpose_to_bf16<<<dim3(32, 4, 1), tb, 0, stream>>>(Wkv, WkvT, 128, 1024);
    transpose_to_bf16<<<dim3(4, 4, 1),  tb, 0, stream>>>(Wsk, WskT, 128, 128);
    transpose_to_bf16<<<dim3(4, 4, 1),  tb, 0, stream>>>(Wsq, WsqT, 128, 128);
    transpose_to_bf16<<<dim3(4, 16, 1), tb, 0, stream>>>(Wo,  WoT,  512, 128);

    // 2) sk / sq projections + tie-row softmax weights
    gemm_nt<64, 128, EpiBiasBF><<<dim3(1, 512, 1), blk, 0, stream>>>(
        xbf, WskT, 0, 0, 128, 128, 128, 0, EpiBiasBF{sk, bsk, 128});
    gemm_nt<64, 128, EpiBiasBF><<<dim3(1, 8, 1), blk, 0, stream>>>(
        xbf, WsqT, 0, 0, 128, 128, 128, 0, EpiBiasBF{sq, bsq, 128});
    rowweight_kernel<<<dim3(1024), blk, 0, stream>>>(sk, sq, w);

    // 3) K,V projection -> Kp (bufB), Vp (bufA); then V transpose -> Vt
    gemm_nt<128, 128, EpiKV><<<dim3(8, 256, 1), blk, 0, stream>>>(
        xbf, WkvT, 0, 0, 128, 128, 128, 0, EpiKV{bufB, bufA});
    transpose64<<<dim3(64, 8, 8), blk, 0, stream>>>(bufA, Vt, 2097152, 2097152, 512, 4096);

    // 4) Q projection with w*scale folded -> Qw (bufA, Vp dead)
    gemm_nt<128, 128, EpiQ><<<dim3(4, 256, 1), blk, 0, stream>>>(
        xbf, WqT, 0, 0, 128, 128, 128, 0, EpiQ{bufA, w});

    // 5) pair-bias LN + projection -> pbd (fp32)
    pb_kernel<<<dim3(4096), blk, 0, stream>>>(pair, Wg, SB, pbd);

    // 6) dots[h] += Qw[h] @ Kp[h]^T (atomic, split-K=8): 1024 blocks = 4/CU
    gemm_nt<128, 128, EpiDotsAtomic><<<dim3(4, 4, 64), blk, 0, stream>>>(
        bufA, bufB, 2097152, 2097152, 4096, 4096, 512, 3, EpiDotsAtomic{pbd});

    // 7) softmax -> attn (bf16, aliases sk region)
    softmax_kernel<<<dim3(1024), blk, 0, stream>>>(pbd, attn);

    // 8) O[h] = attn[h] @ Vt[h]^T -> O2 (bufB, Kp dead)
    gemm_nt<128, 128, EpiPV><<<dim3(32, 4, 8), blk, 0, stream>>>(
        attn, Vt, 262144, 2097152, 512, 512, 512, 0, EpiPV{bufB});

    // 9) final projection: O2 @ Wo + bo -> out (fp32)
    gemm_nt<64, 128, EpiOut><<<dim3(1, 512, 1), blk, 0, stream>>>(
        bufB, WoT, 0, 0, 512, 512, 512, 0, EpiOut{out, bo});
}

// Round 6
// 430.760 us; speedup vs baseline: 1.3837x; 1.3837x over previous
//
#include <hip/hip_runtime.h>
#include <hip/hip_bf16.h>

typedef unsigned short u16;
typedef unsigned int u32;
typedef __attribute__((ext_vector_type(8))) short short8;
typedef __attribute__((ext_vector_type(4))) float floatx4;

__device__ inline float bf2f(u16 u) { union { u32 i; float f; } v; v.i = ((u32)u) << 16; return v.f; }
__device__ inline u16 f2bf(float f) {
    union { float f; u32 i; } v; v.f = f;
    u32 lsb = (v.i >> 16) & 1u;
    v.i += 0x7fffu + lsb;              // round-to-nearest-even
    return (u16)(v.i >> 16);
}

__device__ inline void ld8(u16* dst, const float* src) {
    const float4 a = *(const float4*)src;
    const float4 b = *(const float4*)(src + 4);
    uint4 q;
    q.x = (u32)f2bf(a.x) | ((u32)f2bf(a.y) << 16);
    q.y = (u32)f2bf(a.z) | ((u32)f2bf(a.w) << 16);
    q.z = (u32)f2bf(b.x) | ((u32)f2bf(b.y) << 16);
    q.w = (u32)f2bf(b.z) | ((u32)f2bf(b.w) << 16);
    *(uint4*)dst = q;
}

// async 16B global->LDS DMA; ldst must be wave-uniform (dest = ldst + lane*16)
__device__ inline void async16(u16* ldst, const u16* gsrc) {
    __builtin_amdgcn_global_load_lds((const __attribute__((address_space(1))) u32*)gsrc,
                                     (__attribute__((address_space(3))) u32*)ldst, 16, 0, 0);
}

// ---------------------------------------------------------------------------
// NT GEMM: C[MxN] = A[MxK] @ B[NxK]^T, bf16 in / fp32 MFMA accum.
// Double-buffered LDS + global_load_lds DMA, ONE barrier per K-iter:
//   stage->buf0
//   loop: __syncthreads()  (compiler emits vmcnt(0) drain = buf[cur] ready)
//         stage->buf[1-cur]   // in flight across this iter's compute
//         ds_read + MFMA from buf[cur]
// LDS rows unpadded (LK=32, DMA requires contiguity); XOR chunk swizzle
// (c ^= (row>>1)&3) makes frag ds_read_b128 2-way bank-aliased = free (m136).
// 256 thr = 4 waves (2x2 of 64x64). zlog: split-K over z.
// ---------------------------------------------------------------------------
template <int BM, int BN, class Epi>
__global__ __launch_bounds__(256) void gemm_nt(const u16* __restrict__ A, const u16* __restrict__ B,
                                               long sAz, long sBz, int lda, int ldb, int K, int zlog, Epi epi)
{
    constexpr int AELE = BM * 32, BELE = BN * 32;   // elements per buffer
    constexpr int IA = BM / 64, IB = BN / 64;       // DMA issues per wave
    __shared__ __align__(16) u16 lds[2 * (AELE + BELE)];
    const int tid  = threadIdx.x;
    const int lane = tid & 63;
    const int wave = tid >> 6;
    const int z    = blockIdx.z;
    const int zh   = z >> zlog;
    const int zk   = z & ((1 << zlog) - 1);
    const long row0 = (long)blockIdx.y * BM;
    const long col0 = (long)blockIdx.x * BN;
    const u16* Ab = A + (long)zh * sAz + row0 * lda + (long)zk * K;
    const u16* Bb = B + (long)zh * sBz + col0 * ldb + (long)zk * K;
    constexpr int WM = BM / 2, WN = BN / 2, TM = WM / 16, TN = WN / 16;
    const int wm = (wave >> 1) * WM;
    const int wn = (wave & 1) * WN;
    const int l15 = lane & 15;
    const int quad = lane >> 4;
    const int swz = (l15 >> 1) & 3;   // (row>>1)&3 for row = 16*t + l15

    floatx4 acc[TM][TN];
#pragma unroll
    for (int i = 0; i < TM; i++)
#pragma unroll
        for (int j = 0; j < TN; j++) acc[i][j] = (floatx4){0.f, 0.f, 0.f, 0.f};

    auto stage = [&](int buf, int k0) {
        u16* base = lds + buf * (AELE + BELE);
#pragma unroll
        for (int i = 0; i < IA; i++) {
            int s = wave * (IA * 64) + i * 64 + lane;       // chunk slot
            int r = s >> 2, c = (s & 3) ^ ((r >> 1) & 3);
            async16(base + (wave * (IA * 64) + i * 64) * 8, Ab + (long)r * lda + k0 + c * 8);
        }
        u16* bbase = base + AELE;
#pragma unroll
        for (int i = 0; i < IB; i++) {
            int s = wave * (IB * 64) + i * 64 + lane;
            int r = s >> 2, c = (s & 3) ^ ((r >> 1) & 3);
            async16(bbase + (wave * (IB * 64) + i * 64) * 8, Bb + (long)r * ldb + k0 + c * 8);
        }
    };

    stage(0, 0);
    const int nIter = K >> 5;
    for (int ki = 0; ki < nIter; ki++) {
        const int cur = ki & 1;
        __syncthreads();                         // vmcnt(0) drain: buf[cur] ready
        if (ki + 1 < nIter) stage(1 - cur, (ki + 1) << 5);
        const u16* As = lds + cur * (AELE + BELE);
        const u16* Bs = As + AELE;
        short8 af[TM], bfr[TN];
#pragma unroll
        for (int t = 0; t < TM; t++)
            af[t] = *(const short8*)(As + (wm + t * 16 + l15) * 32 + (quad ^ swz) * 8);
#pragma unroll
        for (int t = 0; t < TN; t++)
            bfr[t] = *(const short8*)(Bs + (wn + t * 16 + l15) * 32 + (quad ^ swz) * 8);
#pragma unroll
        for (int i = 0; i < TM; i++)
#pragma unroll
            for (int j = 0; j < TN; j++)
                acc[i][j] = __builtin_amdgcn_mfma_f32_16x16x32_bf16(af[i], bfr[j], acc[i][j], 0, 0, 0);
    }
#pragma unroll
    for (int i = 0; i < TM; i++)
#pragma unroll
        for (int j = 0; j < TN; j++)
#pragma unroll
            for (int r = 0; r < 4; r++) {
                int row = (int)row0 + wm + i * 16 + quad * 4 + r;
                int col = (int)col0 + wn + j * 16 + l15;
                epi(zh, row, col, acc[i][j][r]);
            }
}

// --- epilogues -------------------------------------------------------------
struct EpiBiasBF {  // C[row*ldc+col] = v + bias[col], bf16 out (sk / sq)
    u16* C; const float* bias; int ldc;
    __device__ void operator()(int, int row, int col, float v) const {
        C[(long)row * ldc + col] = f2bf(v + bias[col]);
    }
};
struct EpiQ {  // rows=(r,i) cols=(h,d) -> Qw[h][i][r*64+d] scaled by w[i,h,r]/8
    u16* Qw; const float* w;
    __device__ void operator()(int, int row, int col, float v) const {
        int r = row >> 9, i = row & 511, h = col >> 6, d = col & 63;
        float s = w[((long)(i * 8 + h)) * 64 + r] * 0.125f;
        Qw[(long)h * 2097152 + (long)i * 4096 + r * 64 + d] = f2bf(v * s);
    }
};
struct EpiKV {  // rows=(r,j) cols 0..511 -> Kp[h][j][rd]; 512..1023 -> Vp[h][j][rd]
    u16* Kp; u16* Vp;
    __device__ void operator()(int, int row, int col, float v) const {
        int r = row >> 9, j = row & 511, d = col & 63;
        u16 val = f2bf(v);
        if (col < 512) Kp[(long)(col >> 6) * 2097152 + (long)j * 4096 + r * 64 + d] = val;
        else           Vp[(long)((col - 512) >> 6) * 2097152 + (long)j * 4096 + r * 64 + d] = val;
    }
};
struct EpiDotsAtomic {  // dots[zh][row][col] += v (pb already resident), fp32
    float* pbdots;
    __device__ void operator()(int zh, int row, int col, float v) const {
        atomicAdd(pbdots + (long)zh * 262144 + (long)row * 512 + col, v);
    }
};
struct EpiPV {  // rows=i, cols=(r,d), z=h -> O2[(r*512+i)][(h*64+d)] bf16
    u16* O2;
    __device__ void operator()(int zh, int row, int col, float v) const {
        int r = col >> 6, d = col & 63;
        O2[((long)r * 512 + row) * 512 + zh * 64 + d] = f2bf(v);
    }
};
struct EpiOut {  // final: out[row*128+col] = v + bo[col], fp32
    float* out; const float* bo;
    __device__ void operator()(int, int row, int col, float v) const {
        out[(long)row * 128 + col] = v + bo[col];
    }
};

// ---------------------------------------------------------------------------
// fp32 -> bf16 bulk convert (8 elems/thread, coalesced)
// ---------------------------------------------------------------------------
__global__ __launch_bounds__(256) void f2bf_kernel(const float* __restrict__ src, u16* __restrict__ dst)
{
    long i = ((long)blockIdx.x * 256 + threadIdx.x) * 8;
    ld8(dst + i, src + i);
}

// ---------------------------------------------------------------------------
// small transpose: src (R x C, fp32) -> dst (C x R, bf16), 32x32 LDS tiles
// ---------------------------------------------------------------------------
__global__ __launch_bounds__(256) void transpose_to_bf16(const float* __restrict__ src, u16* __restrict__ dst,
                                                         int R, int C)
{
    __shared__ u16 t[32][33];
    int c0 = blockIdx.x * 32, r0 = blockIdx.y * 32;
    int tx = threadIdx.x, ty = threadIdx.y;  // 32 x 8
#pragma unroll
    for (int i = 0; i < 32; i += 8) t[ty + i][tx] = f2bf(src[(long)(r0 + ty + i) * C + c0 + tx]);
    __syncthreads();
#pragma unroll
    for (int i = 0; i < 32; i += 8) dst[(long)(c0 + ty + i) * R + r0 + tx] = t[tx][ty + i];
}

// ---------------------------------------------------------------------------
// fast bf16 transpose: 64x64 tiles, 16 B lane transfers both ways, z-batched
// ---------------------------------------------------------------------------
__global__ __launch_bounds__(256) void transpose64(const u16* __restrict__ src, u16* __restrict__ dst,
                                                   long ss, long ds, int R, int C)
{
    __shared__ __align__(16) u16 t[64][72];
    const u16* s = src + (long)blockIdx.z * ss;
    u16* d = dst + (long)blockIdx.z * ds;
    int c0 = blockIdx.x * 64, r0 = blockIdx.y * 64;
    int tid = threadIdx.x;
    int row = tid >> 3, ch = tid & 7;
#pragma unroll
    for (int p = 0; p < 2; p++) {
        int r = row + p * 32;
        *(uint4*)&t[r][ch * 8] = *(const uint4*)(s + (long)(r0 + r) * C + c0 + ch * 8);
    }
    __syncthreads();
#pragma unroll
    for (int p = 0; p < 2; p++) {
        int cc = row + p * 32;
        u16 tmp[8];
#pragma unroll
        for (int j = 0; j < 8; j++) tmp[j] = t[ch * 8 + j][cc];
        *(uint4*)(d + (long)(c0 + cc) * R + r0 + ch * 8) = *(uint4*)tmp;
    }
}

// ---------------------------------------------------------------------------
// Tie-row weights: wave per (i,h); lane = r. logit = <sq[i,h,:],sk[r,i,h,:]>/4
// ---------------------------------------------------------------------------
__global__ __launch_bounds__(256) void rowweight_kernel(const u16* __restrict__ sk, const u16* __restrict__ sq,
                                                        float* __restrict__ w)
{
    int wid = blockIdx.x * 4 + (threadIdx.x >> 6);  // 0..4095 = i*8+h
    int lane = threadIdx.x & 63;                    // r
    int i = wid >> 3, h = wid & 7;
    const u16* sqp = sq + i * 128 + h * 16;
    const u16* skp = sk + ((long)lane * 512 + i) * 128 + h * 16;
    float dot = 0.f;
#pragma unroll
    for (int c = 0; c < 16; c++) dot += bf2f(sqp[c]) * bf2f(skp[c]);
    float logit = dot * 0.25f;
    float m = logit;
#pragma unroll
    for (int o = 32; o > 0; o >>= 1) m = fmaxf(m, __shfl_xor(m, o));
    float e = __expf(logit - m);
    float ssum = e;
#pragma unroll
    for (int o = 32; o > 0; o >>= 1) ssum += __shfl_xor(ssum, o);
    w[(long)wid * 64 + lane] = e / ssum;
}

// ---------------------------------------------------------------------------
// pb prep: Wg[c*8+h] = g[c]*Wp[c*8+h]; SB[h]=sum g*W, SB[8+h]=sum b*W. 1 block.
// ---------------------------------------------------------------------------
__global__ __launch_bounds__(256) void pbprep_kernel(const float* __restrict__ g, const float* __restrict__ b,
                                                     const float* __restrict__ Wp, float* __restrict__ Wg,
                                                     float* __restrict__ SB)
{
    int tid = threadIdx.x;
    for (int t = tid; t < 1024; t += 256) Wg[t] = g[t >> 3] * Wp[t];
    if (tid < 16) {
        int h = tid & 7;
        const float* src = (tid < 8) ? g : b;
        float s = 0.f;
        for (int c = 0; c < 128; c++) s += src[c] * Wp[c * 8 + h];
        SB[tid] = s;
    }
}

// ---------------------------------------------------------------------------
// pair_bias LN + Linear(128->8), LDS-staged, coalesced. 64 rows per block.
// acc_h = rstd*(dot(v,Wg_h) - mu*S_h) + B_h
// ---------------------------------------------------------------------------
__global__ __launch_bounds__(256) void pb_kernel(const float* __restrict__ pair, const float* __restrict__ Wg,
                                                 const float* __restrict__ SB, float* __restrict__ pb)
{
    __shared__ __align__(16) float Ls[64 * 132];
    __shared__ float sWg[1024];
    __shared__ float sSB[16];
    int tid = threadIdx.x;
    for (int t = tid; t < 1024; t += 256) sWg[t] = Wg[t];
    if (tid < 16) sSB[tid] = SB[tid];
    long base = (long)blockIdx.x * 8192;  // 64 rows * 128
    const float4* src = (const float4*)(pair + base);
#pragma unroll
    for (int k = 0; k < 8; k++) {
        int e = tid + k * 256;               // float4 index in tile, 0..2047
        float4 v = src[e];
        int r = e >> 5, c = (e & 31) << 2;
        *(float4*)(&Ls[r * 132 + c]) = v;
    }
    __syncthreads();
    int r = tid >> 2, sub = tid & 3;
    const float* row = &Ls[r * 132];
    float sum = 0.f, sqs = 0.f;
#pragma unroll
    for (int k = 0; k < 8; k++) {
        float4 v = *(const float4*)(&row[sub * 32 + k * 4]);
        sum += v.x + v.y + v.z + v.w;
        sqs += v.x * v.x + v.y * v.y + v.z * v.z + v.w * v.w;
    }
    sum += __shfl_xor(sum, 1); sqs += __shfl_xor(sqs, 1);
    sum += __shfl_xor(sum, 2); sqs += __shfl_xor(sqs, 2);
    float mu = sum * (1.f / 128.f);
    float var = sqs * (1.f / 128.f) - mu * mu;
    float rstd = rsqrtf(var + 1e-5f);
    int h0 = sub * 2;
    float a0 = 0.f, a1 = 0.f;
#pragma unroll
    for (int k = 0; k < 32; k++) {
        float4 v = *(const float4*)(&row[k * 4]);
        int c = k * 4;
        a0 += v.x * sWg[c * 8 + h0]     + v.y * sWg[(c + 1) * 8 + h0]
            + v.z * sWg[(c + 2) * 8 + h0] + v.w * sWg[(c + 3) * 8 + h0];
        a1 += v.x * sWg[c * 8 + h0 + 1]     + v.y * sWg[(c + 1) * 8 + h0 + 1]
            + v.z * sWg[(c + 2) * 8 + h0 + 1] + v.w * sWg[(c + 3) * 8 + h0 + 1];
    }
    long idx = (long)blockIdx.x * 64 + r;
    pb[(long)h0 * 262144 + idx]       = rstd * (a0 - mu * sSB[h0])     + sSB[8 + h0];
    pb[(long)(h0 + 1) * 262144 + idx] = rstd * (a1 - mu * sSB[h0 + 1]) + sSB[8 + h0 + 1];
}

// ---------------------------------------------------------------------------
// Row softmax over 512 cols; wave per row (h*512+i). fp32 in, bf16 out.
// ---------------------------------------------------------------------------
__global__ __launch_bounds__(256) void softmax_kernel(const float* __restrict__ dots, u16* __restrict__ attn)
{
    int row = blockIdx.x * 4 + (threadIdx.x >> 6);
    int lane = threadIdx.x & 63;
    const float* dp = dots + (long)row * 512;
    float v[8];
#pragma unroll
    for (int k = 0; k < 8; k++) v[k] = dp[k * 64 + lane];
    float m = v[0];
#pragma unroll
    for (int k = 1; k < 8; k++) m = fmaxf(m, v[k]);
#pragma unroll
    for (int o = 32; o > 0; o >>= 1) m = fmaxf(m, __shfl_xor(m, o));
    float s = 0.f;
#pragma unroll
    for (int k = 0; k < 8; k++) { v[k] = __expf(v[k] - m); s += v[k]; }
#pragma unroll
    for (int o = 32; o > 0; o >>= 1) s += __shfl_xor(s, o);
    float inv = 1.f / s;
    u16* ap = attn + (long)row * 512;
#pragma unroll
    for (int k = 0; k < 8; k++) ap[k * 64 + lane] = f2bf(v[k] * inv);
}

// ---------------------------------------------------------------------------
extern "C" void kernel_launch(void* const* d_in, const int* in_sizes, int n_in,
                              void* d_out, int out_size, void* d_ws, size_t ws_size,
                              hipStream_t stream)
{
    const float* x    = (const float*)d_in[0];
    const float* pair = (const float*)d_in[1];
    const float* Wq   = (const float*)d_in[2];
    const float* Wkv  = (const float*)d_in[3];
    const float* Wo   = (const float*)d_in[4];
    const float* bo   = (const float*)d_in[5];
    const float* lng  = (const float*)d_in[6];
    const float* lnb  = (const float*)d_in[7];
    const float* Wp   = (const float*)d_in[8];
    const float* Wsq  = (const float*)d_in[9];
    const float* bsq  = (const float*)d_in[10];
    const float* Wsk  = (const float*)d_in[11];
    const float* bsk  = (const float*)d_in[12];
    float* out = (float*)d_out;

    char* ws = (char*)d_ws;
    size_t off = 0;
    auto alloc = [&](size_t bytes) -> char* {
        char* p = ws + off; off += (bytes + 255) & ~(size_t)255; return p;
    };
    u16* WqT  = (u16*)alloc(512 * 128 * 2);
    u16* WkvT = (u16*)alloc(1024 * 128 * 2);
    u16* WskT = (u16*)alloc(128 * 128 * 2);
    u16* WsqT = (u16*)alloc(128 * 128 * 2);
    u16* WoT  = (u16*)alloc(128 * 512 * 2);
    u16* xbf  = (u16*)alloc((size_t)32768 * 128 * 2);
    u16* sk   = (u16*)alloc((size_t)32768 * 128 * 2);   // later reused as attn
    u16* sq   = (u16*)alloc(512 * 128 * 2);
    float* w  = (float*)alloc((size_t)4096 * 64 * 4);
    float* Wg = (float*)alloc(1024 * 4);
    float* SB = (float*)alloc(16 * 4);
    u16* bufA = (u16*)alloc((size_t)8 * 512 * 4096 * 2);  // Vp, then Qw
    u16* bufB = (u16*)alloc((size_t)8 * 512 * 4096 * 2);  // Kp, then O2
    u16* Vt   = (u16*)alloc((size_t)8 * 4096 * 512 * 2);
    float* pbd = (float*)alloc((size_t)8 * 512 * 512 * 4);  // pb, then dots in-place
    u16* attn = sk;  // alias: sk dead after rowweight_kernel

    dim3 blk(256);
    dim3 tb(32, 8);

    // 0) x -> bf16 once; pb prep
    f2bf_kernel<<<dim3(2048), blk, 0, stream>>>(x, xbf);
    pbprep_kernel<<<dim3(1), blk, 0, stream>>>(lng, lnb, Wp, Wg, SB);

    // 1) weight transposes (K x N fp32 -> N x K bf16)
    transpose_to_bf16<<<dim3(16, 4, 1), tb, 0, stream>>>(Wq,  WqT,  128, 512);
    transpose_to_bf16<<<dim3(32, 4, 1), tb, 0, stream>>>(Wkv, WkvT, 128, 1024);
    transpose_to_bf16<<<dim3(4, 4, 1),  tb, 0, stream>>>(Wsk, WskT, 128, 128);
    transpose_to_bf16<<<dim3(4, 4, 1),  tb, 0, stream>>>(Wsq, WsqT, 128, 128);
    transpose_to_bf16<<<dim3(4, 16, 1), tb, 0, stream>>>(Wo,  WoT,  512, 128);

    // 2) sk / sq projections + tie-row softmax weights
    gemm_nt<64, 128, EpiBiasBF><<<dim3(1, 512, 1), blk, 0, stream>>>(
        xbf, WskT, 0, 0, 128, 128, 128, 0, EpiBiasBF{sk, bsk, 128});
    gemm_nt<64, 128, EpiBiasBF><<<dim3(1, 8, 1), blk, 0, stream>>>(
        xbf, WsqT, 0, 0, 128, 128, 128, 0, EpiBiasBF{sq, bsq, 128});
    rowweight_kernel<<<dim3(1024), blk, 0, stream>>>(sk, sq, w);

    // 3) K,V projection -> Kp (bufB), Vp (bufA); then V transpose -> Vt
    gemm_nt<128, 128, EpiKV><<<dim3(8, 256, 1), blk, 0, stream>>>(
        xbf, WkvT, 0, 0, 128, 128, 128, 0, EpiKV{bufB, bufA});
    transpose64<<<dim3(64, 8, 8), blk, 0, stream>>>(bufA, Vt, 2097152, 2097152, 512, 4096);

    // 4) Q projection with w*scale folded -> Qw (bufA, Vp dead)
    gemm_nt<128, 128, EpiQ><<<dim3(4, 256, 1), blk, 0, stream>>>(
        xbf, WqT, 0, 0, 128, 128, 128, 0, EpiQ{bufA, w});

    // 5) pair-bias LN + projection -> pbd (fp32)
    pb_kernel<<<dim3(4096), blk, 0, stream>>>(pair, Wg, SB, pbd);

    // 6) dots[h] += Qw[h] @ Kp[h]^T (atomic, split-K=8): 1024 blocks = 4/CU
    gemm_nt<128, 128, EpiDotsAtomic><<<dim3(4, 4, 64), blk, 0, stream>>>(
        bufA, bufB, 2097152, 2097152, 4096, 4096, 512, 3, EpiDotsAtomic{pbd});

    // 7) softmax -> attn (bf16, aliases sk region)
    softmax_kernel<<<dim3(1024), blk, 0, stream>>>(pbd, attn);

    // 8) O[h] = attn[h] @ Vt[h]^T -> O2 (bufB, Kp dead)
    gemm_nt<128, 128, EpiPV><<<dim3(32, 4, 8), blk, 0, stream>>>(
        attn, Vt, 262144, 2097152, 512, 512, 512, 0, EpiPV{bufB});

    // 9) final projection: O2 @ Wo + bo -> out (fp32)
    gemm_nt<64, 128, EpiOut><<<dim3(1, 512, 1), blk, 0, stream>>>(
        bufB, WoT, 0, 0, 512, 512, 512, 0, EpiOut{out, bo});
}